// Round 1
// baseline (4002.118 us; speedup 1.0000x reference)
//
#include <hip/hip_runtime.h>
#include <stdint.h>

typedef unsigned short u16;
typedef __bf16 bf16x8 __attribute__((ext_vector_type(8)));
typedef float f32x4 __attribute__((ext_vector_type(4)));

#define DEV static __device__ __forceinline__

DEV u16 f2bu(float f) {
    union { float f; unsigned u; } v; v.f = f;
    unsigned r = v.u + 0x7FFFu + ((v.u >> 16) & 1u);
    return (u16)(r >> 16);
}
DEV float b2f(u16 b) {
    union { unsigned u; float f; } v; v.u = ((unsigned)b) << 16;
    return v.f;
}
DEV float fast_tanh(float x) {
    float e = __expf(2.f * x);
    return 1.f - __fdividef(2.f, e + 1.f);
}
DEV float fast_sig(float x) {
    return __fdividef(1.f, 1.f + __expf(-x));
}

// ---------------------------------------------------------------------------
// Generic 128x128 MFMA GEMM, BK=32, 4 waves (2x2), each wave 64x64.
// A: [M][lda]  (bf16, or f32 converted at stage)
// B: B_KXN=false -> [N][ldb] (B^T layout); B_KXN=true -> [K][ldb] f32
// C: [M][ldc]  f32 or bf16
// M,N multiples of 128; K multiple of 32 (enforced by caller).
// LDS row stride 40 (bf16 elems) to dodge bank conflicts.
// ---------------------------------------------------------------------------
template<bool A_F32, bool B_F32, bool B_KXN, bool OUT_BF16, bool BIAS>
__global__ __launch_bounds__(256) void gemm128(
    const void* __restrict__ Ap, int lda,
    const void* __restrict__ Bp, int ldb,
    void* __restrict__ Cp, int ldc,
    const float* __restrict__ bias, int K)
{
    __shared__ u16 As[128 * 40];
    __shared__ u16 Bs[128 * 40];
    const int tid = threadIdx.x;
    const int lane = tid & 63, wave = tid >> 6;
    const int wr = wave >> 1, wc = wave & 1;
    const int m0 = blockIdx.y * 128, n0 = blockIdx.x * 128;

    f32x4 acc[4][4];
#pragma unroll
    for (int m = 0; m < 4; ++m)
#pragma unroll
        for (int n = 0; n < 4; ++n)
            acc[m][n] = (f32x4){0.f, 0.f, 0.f, 0.f};

    for (int k0 = 0; k0 < K; k0 += 32) {
        __syncthreads();
        // ---- stage A tile (128 x 32)
        if (A_F32) {
            const float* A = (const float*)Ap;
#pragma unroll
            for (int i = 0; i < 4; ++i) {
                int c = tid + i * 256;
                int row = c >> 3, kc = (c & 7) * 4;
                float4 v = *(const float4*)&A[(size_t)(m0 + row) * lda + k0 + kc];
                ushort4 o; o.x = f2bu(v.x); o.y = f2bu(v.y); o.z = f2bu(v.z); o.w = f2bu(v.w);
                *(ushort4*)&As[row * 40 + kc] = o;
            }
        } else {
            const u16* A = (const u16*)Ap;
#pragma unroll
            for (int i = 0; i < 2; ++i) {
                int c = tid + i * 256;
                int row = c >> 2, kc = (c & 3) * 8;
                *(int4*)&As[row * 40 + kc] = *(const int4*)&A[(size_t)(m0 + row) * lda + k0 + kc];
            }
        }
        // ---- stage B tile (128 x 32, stored [n][k])
        if (B_KXN) {
            const float* B = (const float*)Bp;
#pragma unroll
            for (int i = 0; i < 4; ++i) {
                int c = tid + i * 256;
                int kk = c >> 5, nc = (c & 31) * 4;
                float4 v = *(const float4*)&B[(size_t)(k0 + kk) * ldb + n0 + nc];
                Bs[(nc + 0) * 40 + kk] = f2bu(v.x);
                Bs[(nc + 1) * 40 + kk] = f2bu(v.y);
                Bs[(nc + 2) * 40 + kk] = f2bu(v.z);
                Bs[(nc + 3) * 40 + kk] = f2bu(v.w);
            }
        } else if (B_F32) {
            const float* B = (const float*)Bp;
#pragma unroll
            for (int i = 0; i < 4; ++i) {
                int c = tid + i * 256;
                int row = c >> 3, kc = (c & 7) * 4;
                float4 v = *(const float4*)&B[(size_t)(n0 + row) * ldb + k0 + kc];
                ushort4 o; o.x = f2bu(v.x); o.y = f2bu(v.y); o.z = f2bu(v.z); o.w = f2bu(v.w);
                *(ushort4*)&Bs[row * 40 + kc] = o;
            }
        } else {
            const u16* B = (const u16*)Bp;
#pragma unroll
            for (int i = 0; i < 2; ++i) {
                int c = tid + i * 256;
                int row = c >> 2, kc = (c & 3) * 8;
                *(int4*)&Bs[row * 40 + kc] = *(const int4*)&B[(size_t)(n0 + row) * ldb + k0 + kc];
            }
        }
        __syncthreads();
        // ---- compute
        const int fr = lane & 15, kq = (lane >> 4) * 8;
        bf16x8 af[4], bq[4];
#pragma unroll
        for (int m = 0; m < 4; ++m)
            af[m] = *(const bf16x8*)&As[(wr * 64 + m * 16 + fr) * 40 + kq];
#pragma unroll
        for (int n = 0; n < 4; ++n)
            bq[n] = *(const bf16x8*)&Bs[(wc * 64 + n * 16 + fr) * 40 + kq];
#pragma unroll
        for (int m = 0; m < 4; ++m)
#pragma unroll
            for (int n = 0; n < 4; ++n)
                acc[m][n] = __builtin_amdgcn_mfma_f32_16x16x32_bf16(af[m], bq[n], acc[m][n], 0, 0, 0);
    }
    // ---- epilogue
    const int fr = lane & 15, rq = (lane >> 4) * 4;
#pragma unroll
    for (int m = 0; m < 4; ++m) {
#pragma unroll
        for (int n = 0; n < 4; ++n) {
            int col = n0 + wc * 64 + n * 16 + fr;
            float bv = BIAS ? bias[col] : 0.f;
#pragma unroll
            for (int r = 0; r < 4; ++r) {
                int row = m0 + wr * 64 + m * 16 + rq + r;
                float v = acc[m][n][r] + bv;
                if (OUT_BF16) ((u16*)Cp)[(size_t)row * ldc + col] = f2bu(v);
                else          ((float*)Cp)[(size_t)row * ldc + col] = v;
            }
        }
    }
}

// ---------------------------------------------------------------------------
// Prologue kernels
// ---------------------------------------------------------------------------

// g^T[d][b] = mean_n img[b][n][d]
__global__ __launch_bounds__(256) void mean_k(const float* __restrict__ img, float* __restrict__ gT)
{
    int b = blockIdx.x >> 3, ch = blockIdx.x & 7;
    int d = ch * 256 + threadIdx.x;
    float s = 0.f;
    for (int n = 0; n < 196; ++n)
        s += img[((size_t)b * 196 + n) * 2048 + d];
    gT[d * 64 + b] = s * (1.f / 196.f);
}

// emb_bf[b*32+t][e] = bf16(embed[tok[b][t]][e])
__global__ __launch_bounds__(256) void emb_gather(const int* __restrict__ tok,
                                                  const float* __restrict__ embed,
                                                  u16* __restrict__ emb_bf)
{
    int id = blockIdx.x * 256 + threadIdx.x;   // 2048*512
    int row = id >> 9, e = id & 511;
    int tk = tok[row];
    emb_bf[(size_t)row * 512 + e] = f2bu(embed[(size_t)tk * 512 + e]);
}

// convert W_hh and W_hid to bf16; bias sum
__global__ __launch_bounds__(256) void conv_weights(const float* __restrict__ Whh,
                                                    const float* __restrict__ Whid,
                                                    const float* __restrict__ bih,
                                                    const float* __restrict__ bhh,
                                                    u16* __restrict__ Whh_bf,
                                                    u16* __restrict__ Whid_bf,
                                                    float* __restrict__ bsum)
{
    int id = blockIdx.x * 256 + threadIdx.x;   // 4456448 total
    if (id < 4194304) Whh_bf[id] = f2bu(Whh[id]);
    else              Whid_bf[id - 4194304] = f2bu(Whid[id - 4194304]);
    if (id < 4096) bsum[id] = bih[id] + bhh[id];
}

// h0/c0 = tanh(g @ W^T + b); writes c f32 and h0 (bf16) into xh0 h-slot
__global__ __launch_bounds__(256) void h0c0(const float* __restrict__ gT,
                                            const float* __restrict__ Wh0, const float* __restrict__ bh0,
                                            const float* __restrict__ Wc0, const float* __restrict__ bc0,
                                            float* __restrict__ c, u16* __restrict__ xh0)
{
    int id = blockIdx.x * 256 + threadIdx.x;   // 65536
    int b = id & 63, n = id >> 6;
    const float4* Wh = (const float4*)&Wh0[(size_t)n * 2048];
    const float4* Wc = (const float4*)&Wc0[(size_t)n * 2048];
    float s0 = 0.f, s1 = 0.f;
#pragma unroll 4
    for (int k4 = 0; k4 < 512; ++k4) {
        float4 wh = Wh[k4], wc = Wc[k4];
        float g0 = gT[(k4 * 4 + 0) * 64 + b];
        float g1 = gT[(k4 * 4 + 1) * 64 + b];
        float g2 = gT[(k4 * 4 + 2) * 64 + b];
        float g3 = gT[(k4 * 4 + 3) * 64 + b];
        s0 += wh.x * g0 + wh.y * g1 + wh.z * g2 + wh.w * g3;
        s1 += wc.x * g0 + wc.y * g1 + wc.z * g2 + wc.w * g3;
    }
    float hv = fast_tanh(s0 + bh0[n]);
    float cv = fast_tanh(s1 + bc0[n]);
    c[b * 1024 + n] = cv;
    xh0[(size_t)b * 3072 + 2048 + n] = f2bu(hv);
}

// ---------------------------------------------------------------------------
// Per-step kernels
// ---------------------------------------------------------------------------

// ph_all[b][a] = h_t @ W_hid^T   (M=64, N=256, K=1024, bf16 MFMA) ; grid=4
__global__ __launch_bounds__(256) void ph_step(const u16* __restrict__ xh_cur,
                                               const u16* __restrict__ Whid_bf,
                                               float* __restrict__ ph_all)
{
    const int tid = threadIdx.x, lane = tid & 63, wave = tid >> 6;
    const int n0 = blockIdx.x * 64;
    __shared__ u16 As[64 * 40], Bs[64 * 40];
    f32x4 acc[4];
#pragma unroll
    for (int m = 0; m < 4; ++m) acc[m] = (f32x4){0.f, 0.f, 0.f, 0.f};

    for (int k0 = 0; k0 < 1024; k0 += 32) {
        __syncthreads();
        {
            int row = tid >> 2, kc = (tid & 3) * 8;
            *(int4*)&As[row * 40 + kc] = *(const int4*)&xh_cur[(size_t)row * 3072 + 2048 + k0 + kc];
            *(int4*)&Bs[row * 40 + kc] = *(const int4*)&Whid_bf[(size_t)(n0 + row) * 1024 + k0 + kc];
        }
        __syncthreads();
        const int fr = lane & 15, kq = (lane >> 4) * 8;
        bf16x8 bq = *(const bf16x8*)&Bs[(wave * 16 + fr) * 40 + kq];
#pragma unroll
        for (int m = 0; m < 4; ++m) {
            bf16x8 af = *(const bf16x8*)&As[(m * 16 + fr) * 40 + kq];
            acc[m] = __builtin_amdgcn_mfma_f32_16x16x32_bf16(af, bq, acc[m], 0, 0, 0);
        }
    }
    const int fr = lane & 15, rq = (lane >> 4) * 4;
#pragma unroll
    for (int m = 0; m < 4; ++m)
#pragma unroll
        for (int r = 0; r < 4; ++r)
            ph_all[(m * 16 + rq + r) * 256 + n0 + wave * 16 + fr] = acc[m][r];
}

// scores + softmax + ctx slice; grid = 64 b * 4 d-quarters = 256 blocks
__global__ __launch_bounds__(256) void attn_ctx(const float* __restrict__ ph_all,
                                                const float* __restrict__ w_score,
                                                const float* __restrict__ proj,  // [64][196][256]
                                                const float* __restrict__ img,   // [64][196][2048]
                                                u16* __restrict__ xh)            // ctx -> [b][0:2048]
{
    const int b = blockIdx.x >> 2, dq = blockIdx.x & 3;
    const int tid = threadIdx.x, lane = tid & 63, wave = tid >> 6;
    __shared__ float ph[256], ws[256], sc[256], red[256];
    ph[tid] = ph_all[b * 256 + tid];
    ws[tid] = w_score[tid];
    if (tid >= 196) sc[tid] = -1e30f;
    __syncthreads();

    // scores: wave w handles rows n = w, w+4, ...
    for (int n = wave; n < 196; n += 4) {
        const float4* P = (const float4*)&proj[((size_t)b * 196 + n) * 256];
        float4 p = P[lane];
        float s = ws[lane * 4 + 0] * fast_tanh(p.x + ph[lane * 4 + 0])
                + ws[lane * 4 + 1] * fast_tanh(p.y + ph[lane * 4 + 1])
                + ws[lane * 4 + 2] * fast_tanh(p.z + ph[lane * 4 + 2])
                + ws[lane * 4 + 3] * fast_tanh(p.w + ph[lane * 4 + 3]);
#pragma unroll
        for (int off = 32; off; off >>= 1) s += __shfl_xor(s, off, 64);
        if (lane == 0) sc[n] = s;
    }
    __syncthreads();

    // softmax over 196 (padded with -1e30)
    red[tid] = sc[tid];
    __syncthreads();
#pragma unroll
    for (int s = 128; s > 0; s >>= 1) {
        if (tid < s) red[tid] = fmaxf(red[tid], red[tid + s]);
        __syncthreads();
    }
    const float mx = red[0];
    __syncthreads();
    float e = (tid < 196) ? __expf(sc[tid] - mx) : 0.f;
    red[tid] = e;
    __syncthreads();
#pragma unroll
    for (int s = 128; s > 0; s >>= 1) {
        if (tid < s) red[tid] += red[tid + s];
        __syncthreads();
    }
    const float inv = __fdividef(1.f, red[0]);
    __syncthreads();
    sc[tid] = e * inv;
    __syncthreads();

    // ctx slice: 512 d-columns, 2 per thread
    int d0 = dq * 512 + tid * 2;
    const float* base = &img[((size_t)b * 196) * 2048 + d0];
    float a0 = 0.f, a1 = 0.f;
#pragma unroll 4
    for (int n = 0; n < 196; ++n) {
        float2 v = *(const float2*)(base + (size_t)n * 2048);
        float w = sc[n];
        a0 += w * v.x;
        a1 += w * v.y;
    }
    ushort2 o; o.x = f2bu(a0); o.y = f2bu(a1);
    *(ushort2*)&xh[(size_t)b * 3072 + d0] = o;
}

// gates MFMA (M=64, N=4 gates x16 cols, K=3072) + fused LSTM pointwise; grid=64
__global__ __launch_bounds__(256) void gates_step(const u16* __restrict__ xh,    // [64][3072] (ctx|h)
                                                  const u16* __restrict__ Wic,   // [4096][2048]
                                                  const u16* __restrict__ Whh,   // [4096][1024]
                                                  const float* __restrict__ xg,  // [64*32][4096]
                                                  float* __restrict__ c,         // [64][1024]
                                                  u16* __restrict__ xh_nxt,      // h -> [b][2048:3072]
                                                  u16* __restrict__ h_all,       // [64*32][1024]
                                                  int t)
{
    const int tid = threadIdx.x, lane = tid & 63, wave = tid >> 6;
    const int hc0 = blockIdx.x * 16;
    __shared__ u16 As[64 * 40];
    __shared__ u16 Bs[4 * 16 * 40];
    __shared__ float gbuf[4][64][17];

    const int fr = lane & 15, kq = (lane >> 4) * 8, rq = (lane >> 4) * 4;

    // acc init = xg (biases already folded in)
    f32x4 acc[4];
#pragma unroll
    for (int m = 0; m < 4; ++m) {
#pragma unroll
        for (int r = 0; r < 4; ++r) {
            int brow = m * 16 + rq + r;
            acc[m][r] = xg[((size_t)brow * 32 + t) * 4096 + wave * 1024 + hc0 + fr];
        }
    }

    const int a_row = tid >> 2, a_kc = (tid & 3) * 8;
    const int b_row = lane >> 2, b_kc = (lane & 3) * 8;
    const int grow = wave * 1024 + hc0 + b_row;

    // K in [0,2048): ctx part vs Wic
    for (int k0 = 0; k0 < 2048; k0 += 32) {
        __syncthreads();
        *(int4*)&As[a_row * 40 + a_kc] = *(const int4*)&xh[(size_t)a_row * 3072 + k0 + a_kc];
        *(int4*)&Bs[(wave * 16 + b_row) * 40 + b_kc] = *(const int4*)&Wic[(size_t)grow * 2048 + k0 + b_kc];
        __syncthreads();
        bf16x8 bq = *(const bf16x8*)&Bs[(wave * 16 + fr) * 40 + kq];
#pragma unroll
        for (int m = 0; m < 4; ++m) {
            bf16x8 af = *(const bf16x8*)&As[(m * 16 + fr) * 40 + kq];
            acc[m] = __builtin_amdgcn_mfma_f32_16x16x32_bf16(af, bq, acc[m], 0, 0, 0);
        }
    }
    // K in [2048,3072): h part vs Whh
    for (int k0 = 0; k0 < 1024; k0 += 32) {
        __syncthreads();
        *(int4*)&As[a_row * 40 + a_kc] = *(const int4*)&xh[(size_t)a_row * 3072 + 2048 + k0 + a_kc];
        *(int4*)&Bs[(wave * 16 + b_row) * 40 + b_kc] = *(const int4*)&Whh[(size_t)grow * 1024 + k0 + b_kc];
        __syncthreads();
        bf16x8 bq = *(const bf16x8*)&Bs[(wave * 16 + fr) * 40 + kq];
#pragma unroll
        for (int m = 0; m < 4; ++m) {
            bf16x8 af = *(const bf16x8*)&As[(m * 16 + fr) * 40 + kq];
            acc[m] = __builtin_amdgcn_mfma_f32_16x16x32_bf16(af, bq, acc[m], 0, 0, 0);
        }
    }

    // dump gate tiles to LDS
    __syncthreads();
#pragma unroll
    for (int m = 0; m < 4; ++m)
#pragma unroll
        for (int r = 0; r < 4; ++r)
            gbuf[wave][m * 16 + rq + r][fr] = acc[m][r];
    __syncthreads();

    // fused LSTM pointwise: 64 b x 16 cols
#pragma unroll
    for (int i = 0; i < 4; ++i) {
        int e = tid + i * 256;
        int bb = e >> 4, jj = e & 15;
        int col = hc0 + jj;
        float ig = fast_sig(gbuf[0][bb][jj]);
        float fg = fast_sig(gbuf[1][bb][jj]);
        float gg = fast_tanh(gbuf[2][bb][jj]);
        float og = fast_sig(gbuf[3][bb][jj]);
        float cp = c[bb * 1024 + col];
        float cn = fg * cp + ig * gg;
        float hn = og * fast_tanh(cn);
        c[bb * 1024 + col] = cn;
        u16 hb = f2bu(hn);
        xh_nxt[(size_t)bb * 3072 + 2048 + col] = hb;
        h_all[((size_t)bb * 32 + t) * 1024 + col] = hb;
    }
}

// ---------------------------------------------------------------------------
extern "C" void kernel_launch(void* const* d_in, const int* in_sizes, int n_in,
                              void* d_out, int out_size, void* d_ws, size_t ws_size,
                              hipStream_t stream)
{
    const float* img     = (const float*)d_in[0];   // [64][196][2048]
    const int*   tok     = (const int*)d_in[1];     // [64][32]
    const float* embed   = (const float*)d_in[2];   // [32000][512]
    const float* W_head1 = (const float*)d_in[3];   // [512][2560]
    const float* W_ih    = (const float*)d_in[4];   // [4096][512]
    const float* W_hh    = (const float*)d_in[5];   // [4096][1024]
    const float* b_ih    = (const float*)d_in[6];   // [4096]
    const float* b_hh    = (const float*)d_in[7];   // [4096]
    const float* W_head  = (const float*)d_in[8];   // [32000][1024]
    const float* W_img   = (const float*)d_in[9];   // [256][2048]
    const float* W_hid   = (const float*)d_in[10];  // [256][1024]
    const float* w_score = (const float*)d_in[11];  // [256]
    const float* W_h0    = (const float*)d_in[12];  // [1024][2048]
    const float* b_h0    = (const float*)d_in[13];  // [1024]
    const float* W_c0    = (const float*)d_in[14];  // [1024][2048]
    const float* b_c0    = (const float*)d_in[15];  // [1024]
    float* out = (float*)d_out;                     // [64][32][32000]

    char* w = (char*)d_ws;
    size_t off = 0;
    auto alloc = [&](size_t bytes) { char* p = w + off; off += (bytes + 255) & ~(size_t)255; return p; };

    u16*   Wic     = (u16*)alloc(4096ULL * 2048 * 2);   // W_ih @ W_head1[:,512:]
    u16*   Whh_bf  = (u16*)alloc(4096ULL * 1024 * 2);
    u16*   Whid_bf = (u16*)alloc(256ULL * 1024 * 2);
    float* xg      = (float*)alloc(2048ULL * 4096 * 4); // emb-path gate pre-acts + biases
    float* proj    = (float*)alloc(64ULL * 196 * 256 * 4);
    u16*   emb_bf  = (u16*)alloc(2048ULL * 512 * 2);
    u16*   xe      = (u16*)alloc(2048ULL * 512 * 2);
    float* gT      = (float*)alloc(2048ULL * 64 * 4);
    float* cbuf    = (float*)alloc(64ULL * 1024 * 4);
    u16*   xhA     = (u16*)alloc(64ULL * 3072 * 2);
    u16*   xhB     = (u16*)alloc(64ULL * 3072 * 2);
    u16*   h_all   = (u16*)alloc(2048ULL * 1024 * 2);
    float* ph_all  = (float*)alloc(64ULL * 256 * 4);
    float* bsum    = (float*)alloc(4096ULL * 4);
    (void)ws_size; (void)in_sizes; (void)n_in; (void)out_size;

    // ---- prologue
    mean_k<<<dim3(512), dim3(256), 0, stream>>>(img, gT);
    emb_gather<<<dim3(4096), dim3(256), 0, stream>>>(tok, embed, emb_bf);
    conv_weights<<<dim3(17408), dim3(256), 0, stream>>>(W_hh, W_hid, b_ih, b_hh, Whh_bf, Whid_bf, bsum);
    h0c0<<<dim3(256), dim3(256), 0, stream>>>(gT, W_h0, b_h0, W_c0, b_c0, cbuf, xhA);

    // xe = emb @ Wa^T  (Wa = W_head1[:, :512])
    gemm128<false, true, false, true, false><<<dim3(4, 16), dim3(256), 0, stream>>>(
        emb_bf, 512, W_head1, 2560, xe, 512, nullptr, 512);
    // xg = xe @ W_ih^T + (b_ih + b_hh)
    gemm128<false, true, false, false, true><<<dim3(32, 16), dim3(256), 0, stream>>>(
        xe, 512, W_ih, 512, xg, 4096, bsum, 512);
    // Wic = W_ih @ W_head1[:, 512:]   (B is [K][N])
    gemm128<true, true, true, true, false><<<dim3(16, 32), dim3(256), 0, stream>>>(
        W_ih, 512, W_head1 + 512, 2560, Wic, 2048, nullptr, 512);
    // proj = img @ W_img^T
    gemm128<true, true, false, false, false><<<dim3(2, 98), dim3(256), 0, stream>>>(
        img, 2048, W_img, 2048, proj, 256, nullptr, 2048);

    // ---- recurrence
    for (int t = 0; t < 32; ++t) {
        u16* xh_cur = (t & 1) ? xhB : xhA;
        u16* xh_nxt = (t & 1) ? xhA : xhB;
        ph_step<<<dim3(4), dim3(256), 0, stream>>>(xh_cur, Whid_bf, ph_all);
        attn_ctx<<<dim3(256), dim3(256), 0, stream>>>(ph_all, w_score, proj, img, xh_cur);
        gates_step<<<dim3(64), dim3(256), 0, stream>>>(xh_cur, Wic, Whh_bf, xg, cbuf, xh_nxt, h_all, t);
    }

    // ---- logits: out = h_all @ W_head^T
    gemm128<false, true, false, false, false><<<dim3(250, 16), dim3(256), 0, stream>>>(
        h_all, 1024, W_head, 1024, out, 32000, nullptr, 1024);
}